// Round 7
// baseline (14.439 us; speedup 1.0000x reference)
//
#include <hip/hip_runtime.h>

// out = W[15,0] * x  (reference collapses: state nonzero only at node 0).
// Memory-bound copy-with-scale: 33.5 MB read + 33.5 MB write (67 MB min).
//
// Ladder: grid-stride 15.96 -> 2048x4+NT 14.09 -> 1024x8 13.75 ->
// 512x16 13.45. NT stores proven win (R3 vs R4). Floor estimate:
// 67.1MB / 6.3TB/s = 10.7us + ~2.3us graph/ramp overhead = ~13.0us.
//
// Final probe on the blocks/ILP axis: 256 blocks x 256 threads x
// 32 float4/thread (1 block/CU, max per-thread MLP). If neutral or
// worse vs 13.45 -> at the bandwidth floor, declare roofline.

typedef float vf4 __attribute__((ext_vector_type(4)));

__global__ __launch_bounds__(256) void ng_scale_kernel(
    const vf4* __restrict__ x,
    const float* __restrict__ W,
    vf4* __restrict__ out)
{
    const float s = W[15 * 16 + 0];  // W[OUT_NODE][IN_NODE]

    int base = blockIdx.x * 8192 + threadIdx.x;

    vf4 v[32];
#pragma unroll
    for (int i = 0; i < 32; ++i)
        v[i] = x[base + i * 256];

#pragma unroll
    for (int i = 0; i < 32; ++i)
        v[i] *= s;

#pragma unroll
    for (int i = 0; i < 32; ++i)
        __builtin_nontemporal_store(v[i], &out[base + i * 256]);
}

extern "C" void kernel_launch(void* const* d_in, const int* in_sizes, int n_in,
                              void* d_out, int out_size, void* d_ws, size_t ws_size,
                              hipStream_t stream) {
    const vf4* x = (const vf4*)d_in[0];
    const float* W = (const float*)d_in[1];
    vf4* out = (vf4*)d_out;

    // n = 2048*4096 = 8388608 floats -> 2097152 float4 -> 256 blocks.
    ng_scale_kernel<<<256, 256, 0, stream>>>(x, W, out);
}

// Round 8
// 13.465 us; speedup vs baseline: 1.0724x; 1.0724x over previous
//
#include <hip/hip_runtime.h>

// out = W[15,0] * x  (reference collapses: state nonzero only at node 0).
// Memory-bound copy-with-scale: 33.5 MB read + 33.5 MB write (67 MB min).
//
// Tuning ladder (all A/B on-device):
//   grid-stride 15.96 -> 2048x4+NT 14.09 -> 1024x8 13.75 ->
//   512x16 13.45 (BEST) -> 256x32 14.44 (occupancy cliff).
// NT stores win over plain (14.09 vs 15.49): write stream bypasses
// L2/L3, x stays cache-hot, full lines stream at fill rate.
// Floor: 67.1MB / 6.3TB/s = 10.7us + ~2.5us launch/ramp = ~13.2us.
// 13.45us is within ~2% of that -> bandwidth roofline.
//
// FINAL: 512 blocks x 256 threads x 16 float4/thread (exact cover).

typedef float vf4 __attribute__((ext_vector_type(4)));

__global__ __launch_bounds__(256) void ng_scale_kernel(
    const vf4* __restrict__ x,
    const float* __restrict__ W,
    vf4* __restrict__ out)
{
    const float s = W[15 * 16 + 0];  // W[OUT_NODE][IN_NODE]

    int base = blockIdx.x * 4096 + threadIdx.x;

    vf4 v[16];
#pragma unroll
    for (int i = 0; i < 16; ++i)
        v[i] = x[base + i * 256];

#pragma unroll
    for (int i = 0; i < 16; ++i)
        v[i] *= s;

#pragma unroll
    for (int i = 0; i < 16; ++i)
        __builtin_nontemporal_store(v[i], &out[base + i * 256]);
}

extern "C" void kernel_launch(void* const* d_in, const int* in_sizes, int n_in,
                              void* d_out, int out_size, void* d_ws, size_t ws_size,
                              hipStream_t stream) {
    const vf4* x = (const vf4*)d_in[0];
    const float* W = (const float*)d_in[1];
    vf4* out = (vf4*)d_out;

    // n = 2048*4096 = 8388608 floats -> 2097152 float4 -> 512 blocks.
    ng_scale_kernel<<<512, 256, 0, stream>>>(x, W, out);
}